// Round 1
// baseline (1768.256 us; speedup 1.0000x reference)
//
#include <hip/hip_runtime.h>
#include <math.h>

#define QN 20000
#define ZN 4
#define PN 80000   // QN*ZN
#define CN 128
#define NVIEW 6

// ---------------- PE input features: sin/cos(pos * 2^j * pi) ----------------
__global__ __launch_bounds__(256) void pe_in_kernel(const float* __restrict__ rp,
                                                    float* __restrict__ pe_in) {
  int idx = blockIdx.x * 256 + threadIdx.x;
  if (idx >= PN * 60) return;
  int p = idx / 60;
  int k = idx - p * 60;
  int q = p >> 2, z = p & 3;
  int d = k / 20;
  int r = k - d * 20;
  int j = (r >= 10) ? (r - 10) : r;
  float pos = rp[((size_t)z * QN + q) * 3 + d];
  float ang = pos * ((float)(1 << j) * 3.14159265358979323846f);
  pe_in[idx] = (r >= 10) ? cosf(ang) : sinf(ang);
}

// ---------------- fp32 SGEMM: C = A[MxK] @ B[KxN] + bias, optional relu ------
// 128x128 tile, BK=8, 256 threads, 8x8 microtile per thread.
// N must be a multiple of 128. M and K arbitrary (K guarded, M guarded).
template <bool RELU>
__global__ __launch_bounds__(256) void sgemm_bias(const float* __restrict__ A,
                                                  const float* __restrict__ B,
                                                  const float* __restrict__ bias,
                                                  float* __restrict__ C,
                                                  int M, int N, int K) {
  __shared__ float As[8][128];
  __shared__ float Bs[8][128];
  const int tid = threadIdx.x;
  const int bm = blockIdx.y * 128;
  const int bn = blockIdx.x * 128;
  const int tx = tid & 15;
  const int ty = tid >> 4;
  float acc[8][8] = {};

  const int arow = tid >> 1;        // 0..127
  const int acol = (tid & 1) * 4;   // 0 or 4
  const int brow = tid >> 5;        // 0..7
  const int bcol = (tid & 31) * 4;  // 0..124

  for (int k0 = 0; k0 < K; k0 += 8) {
    float4 av = make_float4(0.f, 0.f, 0.f, 0.f);
    int gm = bm + arow;
    if (gm < M) {
      if (k0 + acol + 3 < K) {
        av = *(const float4*)(A + (size_t)gm * K + k0 + acol);
      } else {
        float t[4];
        #pragma unroll
        for (int i = 0; i < 4; i++)
          t[i] = (k0 + acol + i < K) ? A[(size_t)gm * K + k0 + acol + i] : 0.f;
        av = make_float4(t[0], t[1], t[2], t[3]);
      }
    }
    As[acol + 0][arow] = av.x;
    As[acol + 1][arow] = av.y;
    As[acol + 2][arow] = av.z;
    As[acol + 3][arow] = av.w;

    float4 bv = make_float4(0.f, 0.f, 0.f, 0.f);
    if (k0 + brow < K) bv = *(const float4*)(B + (size_t)(k0 + brow) * N + bn + bcol);
    *(float4*)(&Bs[brow][bcol]) = bv;

    __syncthreads();
    #pragma unroll
    for (int k = 0; k < 8; k++) {
      float a[8], b[8];
      *(float4*)(a)     = *(const float4*)(&As[k][ty * 8]);
      *(float4*)(a + 4) = *(const float4*)(&As[k][ty * 8 + 4]);
      *(float4*)(b)     = *(const float4*)(&Bs[k][tx * 8]);
      *(float4*)(b + 4) = *(const float4*)(&Bs[k][tx * 8 + 4]);
      #pragma unroll
      for (int i = 0; i < 8; i++)
        #pragma unroll
        for (int jj = 0; jj < 8; jj++) acc[i][jj] += a[i] * b[jj];
    }
    __syncthreads();
  }

  #pragma unroll
  for (int i = 0; i < 8; i++) {
    int row = bm + ty * 8 + i;
    if (row >= M) continue;
    #pragma unroll
    for (int jj = 0; jj < 8; jj += 4) {
      int col = bn + tx * 8 + jj;
      float4 o;
      o.x = acc[i][jj + 0] + bias[col + 0];
      o.y = acc[i][jj + 1] + bias[col + 1];
      o.z = acc[i][jj + 2] + bias[col + 2];
      o.w = acc[i][jj + 3] + bias[col + 3];
      if (RELU) {
        o.x = fmaxf(o.x, 0.f); o.y = fmaxf(o.y, 0.f);
        o.z = fmaxf(o.z, 0.f); o.w = fmaxf(o.w, 0.f);
      }
      *(float4*)(C + (size_t)row * N + col) = o;
    }
  }
}

// ---------------- fused: level-weight softmax + projection + bilinear sample +
//                  view-sum + level-weight + pos_emb add. One wave per point. --
__global__ __launch_bounds__(256) void sample_kernel(
    const float* __restrict__ f0, const float* __restrict__ f1,
    const float* __restrict__ f2, const float* __restrict__ f3,
    const float* __restrict__ rp, const float* __restrict__ l2i,
    const float* __restrict__ wtw, const float* __restrict__ wtb,
    const float* __restrict__ pos_emb, float* __restrict__ X0) {
  __shared__ float sl2i[96];
  __shared__ float swt[516];  // wtw[128*4] then wtb[4]
  const int tid = threadIdx.x;
  if (tid < 96) sl2i[tid] = l2i[tid];
  for (int i = tid; i < 516; i += 256) swt[i] = (i < 512) ? wtw[i] : wtb[i - 512];
  __syncthreads();

  const int wave = tid >> 6, lane = tid & 63;
  const int p = blockIdx.x * 4 + wave;
  const int q = p >> 2, z = p & 3;

  const float x_in = rp[((size_t)z * QN + q) * 3 + 0];
  const float y_in = rp[((size_t)z * QN + q) * 3 + 1];
  const float z_in = rp[((size_t)z * QN + q) * 3 + 2];
  const float X = x_in * 100.f - 50.f;
  const float Y = y_in * 100.f - 50.f;
  const float Zc = z_in * 8.f - 4.f;

  const float* pe = pos_emb + (size_t)p * CN;
  const float e0 = pe[lane];
  const float e1 = pe[lane + 64];

  // level-weight logits: pos_emb @ wtw + wtb, softmax over 4
  float l0 = e0 * swt[lane * 4 + 0] + e1 * swt[(lane + 64) * 4 + 0];
  float l1 = e0 * swt[lane * 4 + 1] + e1 * swt[(lane + 64) * 4 + 1];
  float l2 = e0 * swt[lane * 4 + 2] + e1 * swt[(lane + 64) * 4 + 2];
  float l3 = e0 * swt[lane * 4 + 3] + e1 * swt[(lane + 64) * 4 + 3];
  #pragma unroll
  for (int off = 32; off > 0; off >>= 1) {
    l0 += __shfl_xor(l0, off);
    l1 += __shfl_xor(l1, off);
    l2 += __shfl_xor(l2, off);
    l3 += __shfl_xor(l3, off);
  }
  l0 += swt[512]; l1 += swt[513]; l2 += swt[514]; l3 += swt[515];
  float mx = fmaxf(fmaxf(l0, l1), fmaxf(l2, l3));
  float ex0 = expf(l0 - mx), ex1 = expf(l1 - mx), ex2 = expf(l2 - mx), ex3 = expf(l3 - mx);
  float es = ex0 + ex1 + ex2 + ex3;
  float sw[4] = {ex0 / es, ex1 / es, ex2 / es, ex3 / es};

  const int HH[4] = {64, 32, 16, 8};
  const int WW[4] = {176, 88, 44, 22};
  const float* FT[4] = {f0, f1, f2, f3};

  float acc0 = 0.f, acc1 = 0.f;
  for (int n = 0; n < NVIEW; n++) {
    const float* Mx = sl2i + n * 16;
    float cam0 = Mx[0] * X + Mx[1] * Y + Mx[2]  * Zc + Mx[3];
    float cam1 = Mx[4] * X + Mx[5] * Y + Mx[6]  * Zc + Mx[7];
    float cam2 = Mx[8] * X + Mx[9] * Y + Mx[10] * Zc + Mx[11];
    float denom = fmaxf(cam2, 1e-5f);
    float u = cam0 / denom * (1.f / 704.f);
    float v = cam1 / denom * (1.f / 256.f);
    if (!(cam2 > 1e-5f && u > 0.f && u < 1.f && v > 0.f && v < 1.f)) continue;
    #pragma unroll
    for (int l = 0; l < 4; l++) {
      const int Hl = HH[l], Wl = WW[l];
      float pxl = u * (float)Wl - 0.5f;
      float pyl = v * (float)Hl - 0.5f;
      float fx0 = floorf(pxl), fy0 = floorf(pyl);
      int x0 = (int)fx0, y0 = (int)fy0;
      float wx = pxl - fx0, wy = pyl - fy0;
      float wgt = sw[l];
      float w00 = (1.f - wy) * (1.f - wx) * wgt;
      float w01 = (1.f - wy) * wx * wgt;
      float w10 = wy * (1.f - wx) * wgt;
      float w11 = wy * wx * wgt;
      const float* fb = FT[l] + (size_t)n * Hl * Wl * CN;
      if (y0 >= 0 && y0 < Hl) {
        const float* rowb = fb + (size_t)y0 * Wl * CN;
        if (x0 >= 0 && x0 < Wl) {
          const float* c = rowb + (size_t)x0 * CN;
          acc0 += w00 * c[lane]; acc1 += w00 * c[lane + 64];
        }
        if (x0 + 1 >= 0 && x0 + 1 < Wl) {
          const float* c = rowb + (size_t)(x0 + 1) * CN;
          acc0 += w01 * c[lane]; acc1 += w01 * c[lane + 64];
        }
      }
      if (y0 + 1 >= 0 && y0 + 1 < Hl) {
        const float* rowb = fb + (size_t)(y0 + 1) * Wl * CN;
        if (x0 >= 0 && x0 < Wl) {
          const float* c = rowb + (size_t)x0 * CN;
          acc0 += w10 * c[lane]; acc1 += w10 * c[lane + 64];
        }
        if (x0 + 1 >= 0 && x0 + 1 < Wl) {
          const float* c = rowb + (size_t)(x0 + 1) * CN;
          acc0 += w11 * c[lane]; acc1 += w11 * c[lane + 64];
        }
      }
    }
  }
  X0[(size_t)p * CN + lane] = acc0 + e0;
  X0[(size_t)p * CN + lane + 64] = acc1 + e1;
}

extern "C" void kernel_launch(void* const* d_in, const int* in_sizes, int n_in,
                              void* d_out, int out_size, void* d_ws, size_t ws_size,
                              hipStream_t stream) {
  const float* feat0 = (const float*)d_in[0];
  const float* feat1 = (const float*)d_in[1];
  const float* feat2 = (const float*)d_in[2];
  const float* feat3 = (const float*)d_in[3];
  const float* rp    = (const float*)d_in[4];
  const float* l2i   = (const float*)d_in[5];
  const float* pe_w1 = (const float*)d_in[6];
  const float* pe_b1 = (const float*)d_in[7];
  const float* pe_w2 = (const float*)d_in[8];
  const float* pe_b2 = (const float*)d_in[9];
  const float* wt_w  = (const float*)d_in[10];
  const float* wt_b  = (const float*)d_in[11];
  const float* hm_w1 = (const float*)d_in[12];
  const float* hm_b1 = (const float*)d_in[13];
  const float* hm_w2 = (const float*)d_in[14];
  const float* hm_b2 = (const float*)d_in[15];
  const float* hm_w3 = (const float*)d_in[16];
  const float* hm_b3 = (const float*)d_in[17];
  const float* hm_w4 = (const float*)d_in[18];
  const float* hm_b4 = (const float*)d_in[19];
  float* out = (float*)d_out;

  char* ws = (char*)d_ws;
  // liveness-based aliasing; peak = 204.8 MB
  float* pe_in   = (float*)(ws + 0);          // 80000*60*4  = 19.2 MB
  float* h_pe    = (float*)(ws + 19200000);   // 80000*256*4 = 81.92 MB
  float* pos_emb = (float*)(ws + 101120000);  // 80000*128*4 = 40.96 MB
  float* X0      = (float*)(ws + 0);          // 20000*512*4 = 40.96 MB (pe_in/h_pe dead)
  float* H1      = (float*)(ws + 40960000);   // 20000*1024*4= 81.92 MB (pos_emb dead after sampling)
  float* H2      = (float*)(ws + 122880000);  // 81.92 MB -> end 204.8 MB
  float* H3      = (float*)(ws + 40960000);   // alias H1 (dead)

  // 1. PE features
  pe_in_kernel<<<(PN * 60 + 255) / 256, 256, 0, stream>>>(rp, pe_in);
  // 2. PE MLP: 60 -> 256 (relu) -> 128
  sgemm_bias<true ><<<dim3(256 / 128, (PN + 127) / 128), 256, 0, stream>>>(pe_in, pe_w1, pe_b1, h_pe, PN, 256, 60);
  sgemm_bias<false><<<dim3(128 / 128, (PN + 127) / 128), 256, 0, stream>>>(h_pe, pe_w2, pe_b2, pos_emb, PN, 128, 256);
  // 3. fused softmax + projection + sampling + pos_emb add
  sample_kernel<<<PN / 4, 256, 0, stream>>>(feat0, feat1, feat2, feat3, rp, l2i,
                                            wt_w, wt_b, pos_emb, X0);
  // 4. head MLP: 512 -> 1024 (relu) -> 1024 (relu) -> 1024 (relu) -> 128
  sgemm_bias<true ><<<dim3(1024 / 128, (QN + 127) / 128), 256, 0, stream>>>(X0, hm_w1, hm_b1, H1, QN, 1024, 512);
  sgemm_bias<true ><<<dim3(1024 / 128, (QN + 127) / 128), 256, 0, stream>>>(H1, hm_w2, hm_b2, H2, QN, 1024, 1024);
  sgemm_bias<true ><<<dim3(1024 / 128, (QN + 127) / 128), 256, 0, stream>>>(H2, hm_w3, hm_b3, H3, QN, 1024, 1024);
  sgemm_bias<false><<<dim3(128 / 128, (QN + 127) / 128), 256, 0, stream>>>(H3, hm_w4, hm_b4, out, QN, 128, 1024);
}

// Round 2
// 630.085 us; speedup vs baseline: 2.8064x; 2.8064x over previous
//
#include <hip/hip_runtime.h>
#include <math.h>

#define QN 20000
#define PN 80000   // QN*4
#define CN 128
#define NVIEW 6

typedef __attribute__((ext_vector_type(8))) short bf16x8;
typedef __attribute__((ext_vector_type(4))) float f32x4;

__device__ __forceinline__ unsigned short f2bf(float f) {
  unsigned u = __float_as_uint(f);
  return (unsigned short)((u + 0x7fffu + ((u >> 16) & 1u)) >> 16);
}
__device__ __forceinline__ float bf2f(unsigned short h) {
  return __uint_as_float(((unsigned)h) << 16);
}

__device__ __forceinline__ void gload16(const void* g, void* l) {
  __builtin_amdgcn_global_load_lds(
      (const __attribute__((address_space(1))) void*)g,
      (__attribute__((address_space(3))) void*)l, 16, 0, 0);
}

// ---------------- weight transpose + split: W[K][N] f32 -> Wt_hi/lo[N][Kp] bf16
__global__ __launch_bounds__(256) void wsplit_kernel(const float* __restrict__ W,
                                                     unsigned short* __restrict__ Th,
                                                     unsigned short* __restrict__ Tl,
                                                     int K, int N, int Kp) {
  __shared__ float t[32][33];
  const int n0 = blockIdx.x * 32, k0 = blockIdx.y * 32;
  const int tx = threadIdx.x & 31, ty = threadIdx.x >> 5;  // ty 0..7
  #pragma unroll
  for (int j = 0; j < 4; ++j) {
    int k = k0 + ty + j * 8;
    t[ty + j * 8][tx] = (k < K) ? W[(size_t)k * N + n0 + tx] : 0.f;
  }
  __syncthreads();
  #pragma unroll
  for (int j = 0; j < 4; ++j) {
    int n = n0 + ty + j * 8;
    int k = k0 + tx;
    float v = t[tx][ty + j * 8];
    unsigned short h = f2bf(v);
    Th[(size_t)n * Kp + k] = h;
    Tl[(size_t)n * Kp + k] = f2bf(v - bf2f(h));
  }
}

// ---------------- PE input features, written as split bf16 planes [PN][64] ---
__global__ __launch_bounds__(256) void pe_in_kernel(const float* __restrict__ rp,
                                                    unsigned short* __restrict__ Ph,
                                                    unsigned short* __restrict__ Pl) {
  int idx = blockIdx.x * 256 + threadIdx.x;
  if (idx >= PN * 64) return;
  int p = idx >> 6, k = idx & 63;
  float val = 0.f;
  if (k < 60) {
    int q = p >> 2, z = p & 3;
    int d = k / 20, r = k - d * 20;
    int j = (r >= 10) ? (r - 10) : r;
    float pos = rp[((size_t)z * QN + q) * 3 + d];
    float ang = pos * ((float)(1 << j) * 3.14159265358979323846f);
    val = (r >= 10) ? cosf(ang) : sinf(ang);
  }
  unsigned short h = f2bf(val);
  Ph[idx] = h;
  Pl[idx] = f2bf(val - bf2f(h));
}

// ---------------- split-bf16 MFMA GEMM -------------------------------------
// C[M][N] = (Ah+Al)[M][K] @ (Bh+Bl)^T[N][K] + bias, 3-term MFMA (hh, hl, lh).
// 128x128 tile, BK=64, 256 threads (4 waves, 2x2 wave grid, 64x64 per wave).
// OUT=0: fp32 C. OUT=1: split bf16 planes Ch, Cl. N % 128 == 0, K % 64 == 0.
template <bool RELU, int OUT>
__global__ __launch_bounds__(256, 2) void gemm3(const unsigned short* __restrict__ Ah,
                                                const unsigned short* __restrict__ Al,
                                                const unsigned short* __restrict__ Bh,
                                                const unsigned short* __restrict__ Bl,
                                                const float* __restrict__ bias,
                                                float* __restrict__ Cf,
                                                unsigned short* __restrict__ Ch,
                                                unsigned short* __restrict__ Cl,
                                                int M, int N, int K) {
  __shared__ short sm[4 * 8192];  // 64KB: Ah, Al, Bh, Bl tiles [128][64] bf16
  const int tid = threadIdx.x;
  const int wave = tid >> 6, lane = tid & 63;
  const int wr = wave >> 1, wc = wave & 1;
  const int bm = blockIdx.y * 128, bn = blockIdx.x * 128;

  f32x4 acc[4][4];
  #pragma unroll
  for (int i = 0; i < 4; ++i)
    #pragma unroll
    for (int j = 0; j < 4; ++j) acc[i][j] = {0.f, 0.f, 0.f, 0.f};

  const int g = lane >> 4, r16 = lane & 15;

  for (int k0 = 0; k0 < K; k0 += 64) {
    __syncthreads();
    // stage 4 x 16KB tiles; LDS linear, source pre-swizzled (slot ^= row&7)
    #pragma unroll
    for (int i = 0; i < 4; ++i) {
      int ii = wave * 4 + i;
      int row = ii * 8 + (lane >> 3);
      int slot = (lane & 7) ^ (row & 7);
      int gcol = k0 + slot * 8;
      size_t so = (size_t)ii * 512;  // shorts per 1KB instr
      int ra = bm + row; if (ra >= M) ra = M - 1;
      int rb = bn + row;
      gload16(Ah + (size_t)ra * K + gcol, &sm[0 * 8192 + so]);
      gload16(Al + (size_t)ra * K + gcol, &sm[1 * 8192 + so]);
      gload16(Bh + (size_t)rb * K + gcol, &sm[2 * 8192 + so]);
      gload16(Bl + (size_t)rb * K + gcol, &sm[3 * 8192 + so]);
    }
    __syncthreads();  // compiler emits vmcnt(0) drain before barrier

    #pragma unroll
    for (int kk = 0; kk < 2; ++kk) {
      bf16x8 ah[4], al[4], bh[4], bl[4];
      #pragma unroll
      for (int mi = 0; mi < 4; ++mi) {
        int row = wr * 64 + mi * 16 + r16;
        int idx = row * 64 + (((kk * 4 + g) ^ (row & 7)) * 8);
        ah[mi] = *(const bf16x8*)&sm[0 * 8192 + idx];
        al[mi] = *(const bf16x8*)&sm[1 * 8192 + idx];
      }
      #pragma unroll
      for (int ni = 0; ni < 4; ++ni) {
        int row = wc * 64 + ni * 16 + r16;
        int idx = row * 64 + (((kk * 4 + g) ^ (row & 7)) * 8);
        bh[ni] = *(const bf16x8*)&sm[2 * 8192 + idx];
        bl[ni] = *(const bf16x8*)&sm[3 * 8192 + idx];
      }
      #pragma unroll
      for (int mi = 0; mi < 4; ++mi)
        #pragma unroll
        for (int ni = 0; ni < 4; ++ni)
          acc[mi][ni] = __builtin_amdgcn_mfma_f32_16x16x32_bf16(ah[mi], bh[ni], acc[mi][ni], 0, 0, 0);
      #pragma unroll
      for (int mi = 0; mi < 4; ++mi)
        #pragma unroll
        for (int ni = 0; ni < 4; ++ni)
          acc[mi][ni] = __builtin_amdgcn_mfma_f32_16x16x32_bf16(ah[mi], bl[ni], acc[mi][ni], 0, 0, 0);
      #pragma unroll
      for (int mi = 0; mi < 4; ++mi)
        #pragma unroll
        for (int ni = 0; ni < 4; ++ni)
          acc[mi][ni] = __builtin_amdgcn_mfma_f32_16x16x32_bf16(al[mi], bh[ni], acc[mi][ni], 0, 0, 0);
    }
  }

  // epilogue: D row = (lane>>4)*4 + r, col = lane&15 within each 16x16 frag
  #pragma unroll
  for (int mi = 0; mi < 4; ++mi) {
    int gr0 = bm + wr * 64 + mi * 16 + (lane >> 4) * 4;
    #pragma unroll
    for (int ni = 0; ni < 4; ++ni) {
      int gc = bn + wc * 64 + ni * 16 + (lane & 15);
      float bv = bias[gc];
      #pragma unroll
      for (int r = 0; r < 4; ++r) {
        int row = gr0 + r;
        if (row >= M) continue;
        float v = acc[mi][ni][r] + bv;
        if (RELU) v = fmaxf(v, 0.f);
        if (OUT == 0) {
          Cf[(size_t)row * N + gc] = v;
        } else {
          unsigned short h = f2bf(v);
          Ch[(size_t)row * N + gc] = h;
          Cl[(size_t)row * N + gc] = f2bf(v - bf2f(h));
        }
      }
    }
  }
}

// ---------------- fused softmax + projection + bilinear sample --------------
__global__ __launch_bounds__(256) void sample_kernel(
    const float* __restrict__ f0, const float* __restrict__ f1,
    const float* __restrict__ f2, const float* __restrict__ f3,
    const float* __restrict__ rp, const float* __restrict__ l2i,
    const float* __restrict__ wtw, const float* __restrict__ wtb,
    const float* __restrict__ pos_emb,
    unsigned short* __restrict__ X0h, unsigned short* __restrict__ X0l) {
  __shared__ float sl2i[96];
  __shared__ float swt[516];
  const int tid = threadIdx.x;
  if (tid < 96) sl2i[tid] = l2i[tid];
  for (int i = tid; i < 516; i += 256) swt[i] = (i < 512) ? wtw[i] : wtb[i - 512];
  __syncthreads();

  const int wave = tid >> 6, lane = tid & 63;
  const int p = blockIdx.x * 4 + wave;
  const int q = p >> 2, z = p & 3;

  const float x_in = rp[((size_t)z * QN + q) * 3 + 0];
  const float y_in = rp[((size_t)z * QN + q) * 3 + 1];
  const float z_in = rp[((size_t)z * QN + q) * 3 + 2];
  const float X = x_in * 100.f - 50.f;
  const float Y = y_in * 100.f - 50.f;
  const float Zc = z_in * 8.f - 4.f;

  const float* pe = pos_emb + (size_t)p * CN;
  const float e0 = pe[lane];
  const float e1 = pe[lane + 64];

  float l0 = e0 * swt[lane * 4 + 0] + e1 * swt[(lane + 64) * 4 + 0];
  float l1 = e0 * swt[lane * 4 + 1] + e1 * swt[(lane + 64) * 4 + 1];
  float l2 = e0 * swt[lane * 4 + 2] + e1 * swt[(lane + 64) * 4 + 2];
  float l3 = e0 * swt[lane * 4 + 3] + e1 * swt[(lane + 64) * 4 + 3];
  #pragma unroll
  for (int off = 32; off > 0; off >>= 1) {
    l0 += __shfl_xor(l0, off);
    l1 += __shfl_xor(l1, off);
    l2 += __shfl_xor(l2, off);
    l3 += __shfl_xor(l3, off);
  }
  l0 += swt[512]; l1 += swt[513]; l2 += swt[514]; l3 += swt[515];
  float mx = fmaxf(fmaxf(l0, l1), fmaxf(l2, l3));
  float ex0 = expf(l0 - mx), ex1 = expf(l1 - mx), ex2 = expf(l2 - mx), ex3 = expf(l3 - mx);
  float es = ex0 + ex1 + ex2 + ex3;
  float sw[4] = {ex0 / es, ex1 / es, ex2 / es, ex3 / es};

  const int HH[4] = {64, 32, 16, 8};
  const int WW[4] = {176, 88, 44, 22};
  const float* FT[4] = {f0, f1, f2, f3};

  float acc0 = 0.f, acc1 = 0.f;
  for (int n = 0; n < NVIEW; n++) {
    const float* Mx = sl2i + n * 16;
    float cam0 = Mx[0] * X + Mx[1] * Y + Mx[2]  * Zc + Mx[3];
    float cam1 = Mx[4] * X + Mx[5] * Y + Mx[6]  * Zc + Mx[7];
    float cam2 = Mx[8] * X + Mx[9] * Y + Mx[10] * Zc + Mx[11];
    float denom = fmaxf(cam2, 1e-5f);
    float u = cam0 / denom * (1.f / 704.f);
    float v = cam1 / denom * (1.f / 256.f);
    if (!(cam2 > 1e-5f && u > 0.f && u < 1.f && v > 0.f && v < 1.f)) continue;
    #pragma unroll
    for (int l = 0; l < 4; l++) {
      const int Hl = HH[l], Wl = WW[l];
      float pxl = u * (float)Wl - 0.5f;
      float pyl = v * (float)Hl - 0.5f;
      float fx0 = floorf(pxl), fy0 = floorf(pyl);
      int x0 = (int)fx0, y0 = (int)fy0;
      float wx = pxl - fx0, wy = pyl - fy0;
      float wgt = sw[l];
      float w00 = (1.f - wy) * (1.f - wx) * wgt;
      float w01 = (1.f - wy) * wx * wgt;
      float w10 = wy * (1.f - wx) * wgt;
      float w11 = wy * wx * wgt;
      const float* fb = FT[l] + (size_t)n * Hl * Wl * CN;
      if (y0 >= 0 && y0 < Hl) {
        const float* rowb = fb + (size_t)y0 * Wl * CN;
        if (x0 >= 0 && x0 < Wl) {
          const float* c = rowb + (size_t)x0 * CN;
          acc0 += w00 * c[lane]; acc1 += w00 * c[lane + 64];
        }
        if (x0 + 1 >= 0 && x0 + 1 < Wl) {
          const float* c = rowb + (size_t)(x0 + 1) * CN;
          acc0 += w01 * c[lane]; acc1 += w01 * c[lane + 64];
        }
      }
      if (y0 + 1 >= 0 && y0 + 1 < Hl) {
        const float* rowb = fb + (size_t)(y0 + 1) * Wl * CN;
        if (x0 >= 0 && x0 < Wl) {
          const float* c = rowb + (size_t)x0 * CN;
          acc0 += w10 * c[lane]; acc1 += w10 * c[lane + 64];
        }
        if (x0 + 1 >= 0 && x0 + 1 < Wl) {
          const float* c = rowb + (size_t)(x0 + 1) * CN;
          acc0 += w11 * c[lane]; acc1 += w11 * c[lane + 64];
        }
      }
    }
  }
  float v0 = acc0 + e0;
  float v1 = acc1 + e1;
  size_t base = (size_t)p * CN;   // == q*512 + z*128
  unsigned short h0 = f2bf(v0), h1 = f2bf(v1);
  X0h[base + lane] = h0;        X0l[base + lane] = f2bf(v0 - bf2f(h0));
  X0h[base + lane + 64] = h1;   X0l[base + lane + 64] = f2bf(v1 - bf2f(h1));
}

extern "C" void kernel_launch(void* const* d_in, const int* in_sizes, int n_in,
                              void* d_out, int out_size, void* d_ws, size_t ws_size,
                              hipStream_t stream) {
  const float* feat0 = (const float*)d_in[0];
  const float* feat1 = (const float*)d_in[1];
  const float* feat2 = (const float*)d_in[2];
  const float* feat3 = (const float*)d_in[3];
  const float* rp    = (const float*)d_in[4];
  const float* l2i   = (const float*)d_in[5];
  const float* pe_w1 = (const float*)d_in[6];
  const float* pe_b1 = (const float*)d_in[7];
  const float* pe_w2 = (const float*)d_in[8];
  const float* pe_b2 = (const float*)d_in[9];
  const float* wt_w  = (const float*)d_in[10];
  const float* wt_b  = (const float*)d_in[11];
  const float* hm_w1 = (const float*)d_in[12];
  const float* hm_b1 = (const float*)d_in[13];
  const float* hm_w2 = (const float*)d_in[14];
  const float* hm_b2 = (const float*)d_in[15];
  const float* hm_w3 = (const float*)d_in[16];
  const float* hm_b3 = (const float*)d_in[17];
  const float* hm_w4 = (const float*)d_in[18];
  const float* hm_b4 = (const float*)d_in[19];
  float* out = (float*)d_out;

  char* ws = (char*)d_ws;
  typedef unsigned short us;
  // --- weight hi/lo transposed planes [N][Kp], bytes ---
  us* wPE1h = (us*)(ws + 0);         // 256x64
  us* wPE1l = (us*)(ws + 32768);
  us* wPE2h = (us*)(ws + 65536);     // 128x256
  us* wPE2l = (us*)(ws + 131072);
  us* wH1h  = (us*)(ws + 196608);    // 1024x512
  us* wH1l  = (us*)(ws + 1245184);
  us* wH2h  = (us*)(ws + 2293760);   // 1024x1024
  us* wH2l  = (us*)(ws + 4390912);
  us* wH3h  = (us*)(ws + 6488064);   // 1024x1024
  us* wH3l  = (us*)(ws + 8585216);
  us* wH4h  = (us*)(ws + 10682368);  // 128x1024
  us* wH4l  = (us*)(ws + 10944512);  // ends 11,206,656

  // --- activations (liveness-aliased) ---
  us*    peinH = (us*)(ws + 12000000);    // [80000][64]
  us*    peinL = (us*)(ws + 22240000);
  us*    X0h   = (us*)(ws + 12000000);    // [20000][512] (pe_in dead)
  us*    X0l   = (us*)(ws + 32480000);
  float* posE  = (float*)(ws + 53000000); // [80000][128] f32
  us*    hpeH  = (us*)(ws + 94000000);    // [80000][256]
  us*    hpeL  = (us*)(ws + 134960000);
  us*    H1h   = (us*)(ws + 94000000);    // [20000][1024] (hpe dead)
  us*    H1l   = (us*)(ws + 134960000);
  us*    H2h   = (us*)(ws + 12000000);    // (X0, posE dead)
  us*    H2l   = (us*)(ws + 52960000);
  us*    H3h   = (us*)(ws + 94000000);    // (H1 dead)
  us*    H3l   = (us*)(ws + 134960000);

  // 0. weight transpose+split (6 small kernels)
  wsplit_kernel<<<dim3(8, 2),   256, 0, stream>>>(pe_w1, wPE1h, wPE1l, 60,   256,  64);
  wsplit_kernel<<<dim3(4, 8),   256, 0, stream>>>(pe_w2, wPE2h, wPE2l, 256,  128,  256);
  wsplit_kernel<<<dim3(32, 16), 256, 0, stream>>>(hm_w1, wH1h,  wH1l,  512,  1024, 512);
  wsplit_kernel<<<dim3(32, 32), 256, 0, stream>>>(hm_w2, wH2h,  wH2l,  1024, 1024, 1024);
  wsplit_kernel<<<dim3(32, 32), 256, 0, stream>>>(hm_w3, wH3h,  wH3l,  1024, 1024, 1024);
  wsplit_kernel<<<dim3(4, 32),  256, 0, stream>>>(hm_w4, wH4h,  wH4l,  1024, 128,  1024);

  // 1. PE features (split planes, K padded 60->64)
  pe_in_kernel<<<(PN * 64 + 255) / 256, 256, 0, stream>>>(rp, peinH, peinL);

  // 2. PE MLP: 64 -> 256 (relu, split out) -> 128 (f32 out)
  gemm3<true, 1><<<dim3(2, 625), 256, 0, stream>>>(peinH, peinL, wPE1h, wPE1l, pe_b1,
                                                   nullptr, hpeH, hpeL, PN, 256, 64);
  gemm3<false, 0><<<dim3(1, 625), 256, 0, stream>>>(hpeH, hpeL, wPE2h, wPE2l, pe_b2,
                                                    posE, nullptr, nullptr, PN, 128, 256);

  // 3. fused softmax + projection + sampling (writes X0 split planes)
  sample_kernel<<<PN / 4, 256, 0, stream>>>(feat0, feat1, feat2, feat3, rp, l2i,
                                            wt_w, wt_b, posE, X0h, X0l);

  // 4. head MLP: 512 -> 1024 -> 1024 -> 1024 -> 128
  gemm3<true, 1><<<dim3(8, 157), 256, 0, stream>>>(X0h, X0l, wH1h, wH1l, hm_b1,
                                                   nullptr, H1h, H1l, QN, 1024, 512);
  gemm3<true, 1><<<dim3(8, 157), 256, 0, stream>>>(H1h, H1l, wH2h, wH2l, hm_b2,
                                                   nullptr, H2h, H2l, QN, 1024, 1024);
  gemm3<true, 1><<<dim3(8, 157), 256, 0, stream>>>(H2h, H2l, wH3h, wH3l, hm_b3,
                                                   nullptr, H3h, H3l, QN, 1024, 1024);
  gemm3<false, 0><<<dim3(1, 157), 256, 0, stream>>>(H3h, H3l, wH4h, wH4l, hm_b4,
                                                    out, nullptr, nullptr, QN, 128, 1024);
}